// Round 8
// baseline (304.608 us; speedup 1.0000x reference)
//
#include <hip/hip_runtime.h>
#include <cstdint>
#include <cstddef>

#define MDIM 4096   // batch
#define NDIM 4096   // out features
#define KDIM 4096   // in features

typedef _Float16 half8   __attribute__((ext_vector_type(8)));
typedef float    floatx4 __attribute__((ext_vector_type(4)));

// Hamilton product tables: out_comp = sum_c sign[comp][c] * (x_c @ W_{comp^c}^T)
__device__ __constant__ int   d_qtab[16] = {0,1,2,3,  1,0,3,2,  2,3,0,1,  3,2,1,0};
__device__ __constant__ float d_stab[16] = {1.f,-1.f,-1.f,-1.f,
                                            1.f, 1.f, 1.f,-1.f,
                                            1.f,-1.f, 1.f, 1.f,
                                            1.f, 1.f,-1.f, 1.f};

// ---------------- prepass: cast W only -> fp16 (24 MB traffic, ~5 us) --------
// R8: the x-cast (96 MB, 8192 blocks) is FUSED into the gemm's A-staging; the
// serial prepass+gap residual (total - gemm = 110..131 us across R0..R7,
// ~constant) was dominated by it.
__global__ void prepass_kernel(const float* __restrict__ W0, const float* __restrict__ W1,
                               const float* __restrict__ W2, const float* __restrict__ W3,
                               _Float16* __restrict__ Wh) {
    int idx = blockIdx.x * 256 + threadIdx.x;      // 0 .. 512K-1
    int e = idx << 3;                               // 0 .. 4M-1
    int m = e >> 20;
    int off = e & ((1 << 20) - 1);
    const float* Ws[4] = {W0, W1, W2, W3};
    const float* src = Ws[m] + off;
    float4 a = *(const float4*)src;
    float4 v = *(const float4*)(src + 4);
    half8 h = {(_Float16)a.x, (_Float16)a.y, (_Float16)a.z, (_Float16)a.w,
               (_Float16)v.x, (_Float16)v.y, (_Float16)v.z, (_Float16)v.w};
    *(half8*)(Wh + ((size_t)m << 20) + off) = h;
}

// --- MFMA GEMM: 256x256, BK=64, 8 waves; fused fp32->fp16 A-staging ----------
// Compute phases are verbatim R3 (best-measured: 135us/46%). Staging changes:
//  A: reg-staged from fp32 x. Per thread per tile: 8x float4 loads (ph1, for
//     tile t1), 32 RTE casts + 4 ds_write_b128 (ph3, into nxt). Same LDS
//     layout as the old DMA (chunk c=g*2+half at AsSt + buf*16384 + c*4096;
//     source row m0 + (c>>1)*64 + (c&1)*128 + lrow, k = t1*64 + gch*8).
//  B: global_load_lds DMA unchanged, both halves at ph2 (into nxt).
// vmcnt ledger (per-wave FIFO, zero carry across tiles):
//  ph1 issues A8(t1) -> ph2 issues B4(t1) -> ph3 WAITVM(4) retires exactly A8
//  (B4 newer, stays) -> ph4 WAITVM(0) retires exactly B4. Compiler-inserted
//  waits for aS* register uses are consistent (gload_lds is modeled in vmcnt).
// Publication/WAR:
//  A ds_write ph3(tt)->nxt: region's last reads t-1 ph3/ph4, drained by their
//    lgkm0 >= 3 BARs earlier; writes drain at ph3 lgkm0, published ph3 BAR,
//    read t+1 ph1 (>=2 BARs later).
//  B DMA ph2(tt)->nxt: last reads t-1 ph1/ph2 (>=4 BARs); retired ph4
//    WAITVM(0), published ph4 BAR, read t+1 ph1.
// Tail: t1 clamps to 63 (dead re-stage into nxt, never consumed, in-bounds).
// Signs (R6/R7-proven): acc flip at negseg boundaries + epilogue esign.
// LDS: rows of 64 halves (128B), slot = chunk ^ (row&7) (0 conflicts measured).

__device__ __forceinline__ void gload_lds16(const _Float16* g, _Float16* l) {
    __builtin_amdgcn_global_load_lds(
        (const __attribute__((address_space(1))) unsigned int*)g,
        (__attribute__((address_space(3))) unsigned int*)l,
        16, 0, 0);
}

#define BAR __builtin_amdgcn_s_barrier()
#define SCHEDB __builtin_amdgcn_sched_barrier(0)
#define WAITVM(N) asm volatile("s_waitcnt vmcnt(" #N ")" ::: "memory")
#define WAITLGKM0 do { asm volatile("s_waitcnt lgkmcnt(0)" ::: "memory"); \
                       SCHEDB; } while (0)

// issue 8 fp32 A loads for K-tile TT (chunks c=0..3 = rows +0,+128,+64,+192)
#define AISSUE(TT) { \
    const float* _a = Xbase + (TT) * 64; \
    aS0 = *(const float4*)(_a);                      \
    aS1 = *(const float4*)(_a + 4);                  \
    aS2 = *(const float4*)(_a + (size_t)128 * 4096); \
    aS3 = *(const float4*)(_a + (size_t)128 * 4096 + 4); \
    aS4 = *(const float4*)(_a + (size_t)64 * 4096);  \
    aS5 = *(const float4*)(_a + (size_t)64 * 4096 + 4); \
    aS6 = *(const float4*)(_a + (size_t)192 * 4096); \
    aS7 = *(const float4*)(_a + (size_t)192 * 4096 + 4); }

__device__ __forceinline__ half8 cvt8(float4 a, float4 b) {
    return (half8){(_Float16)a.x, (_Float16)a.y, (_Float16)a.z, (_Float16)a.w,
                   (_Float16)b.x, (_Float16)b.y, (_Float16)b.z, (_Float16)b.w};
}

// convert + write the 4 staged chunks into buffer BUF (c*4096 = g*8192+half*4096)
#define CVTWR(BUF) { \
    _Float16* _d = AsSt + (BUF) * 16384; \
    *(half8*)(_d)         = cvt8(aS0, aS1); \
    *(half8*)(_d +  4096) = cvt8(aS2, aS3); \
    *(half8*)(_d +  8192) = cvt8(aS4, aS5); \
    *(half8*)(_d + 12288) = cvt8(aS6, aS7); }

// stage B n-half h (cols h*128..+127) of K-tile tt into buffer buf (DMA)
#define STB(h, tt, buf) { \
    const int _sg = (tt) >> 4; \
    const _Float16* _s = Bbase + ((size_t)(comp ^ _sg) << 20) \
                       + (size_t)((h) * 128) * 1024 + ((tt) & 15) * 64; \
    _Float16* _d = BsSt + (buf) * 16384 + (h) * 8192; \
    gload_lds16(_s, _d); \
    gload_lds16(_s + 64 * 1024, _d + 4096); }

#define RDA(AF, BASE, g, SL) { \
    const _Float16* _p = (BASE) + (g) * 8192 + arow + (SL); \
    AF[0] = *(const half8*)(_p); \
    AF[1] = *(const half8*)(_p + 1024); \
    AF[2] = *(const half8*)(_p + 2048); \
    AF[3] = *(const half8*)(_p + 3072); }

#define RDB(BQ, BASE, SL) { \
    const _Float16* _p = (BASE) + bnh * 8192 + brow + (SL); \
    BQ[0] = *(const half8*)(_p); \
    BQ[1] = *(const half8*)(_p + 1024); \
    BQ[2] = *(const half8*)(_p + 2048); \
    BQ[3] = *(const half8*)(_p + 3072); }

#define MFMA16(IB, AF, BQ) \
    _Pragma("unroll") \
    for (int _i = 0; _i < 4; _i++) \
      _Pragma("unroll") \
      for (int _j = 0; _j < 4; _j++) \
        acc[(IB) + _i][_j] = __builtin_amdgcn_mfma_f32_16x16x32_f16( \
            AF[_i], BQ[_j], acc[(IB) + _i][_j], 0, 0, 0);

__global__ __launch_bounds__(512, 2) void gemm_kernel(
        const float* __restrict__ X,         // [4096,4096] fp32 (raw input)
        const _Float16* __restrict__ Wh,     // [4][1024][1024] fp16
        const float* __restrict__ b0, const float* __restrict__ b1,
        const float* __restrict__ b2, const float* __restrict__ b3,
        float* __restrict__ C) {
    __shared__ _Float16 lds[65536];          // 128 KiB
    _Float16* As = lds;                      // [buf][g][8192]
    _Float16* Bs = lds + 32768;              // [buf][h][8192]

    const int tid  = threadIdx.x;
    const int lane = tid & 63;
    const int wave = tid >> 6;               // 0..7
    const int wmh  = wave >> 2;              // M-half of 256-row tile (0/1)
    const int wn   = (wave & 3) * 64;        // N offset within 256-col tile
    const int bnh  = wn >> 7;                // which B region this wave reads
    const int broff = (wn & 64) * 64;        // 4K-block within B region

    // bijective XCD swizzle (nwg=256): each XCD gets 2 full bm-rows
    const int wg = ((blockIdx.x & 7) << 5) | (blockIdx.x >> 3);
    const int bm = wg >> 4, bn = wg & 15;
    const int m0 = bm << 8;
    const int n0 = bn << 8;
    const int comp = bn >> 2;                // output quaternion component
    const int n0q  = n0 & 1023;

    // staging geometry: 8 threads/row, 16B chunks, slot s holds chunk s^(row&7)
    const int lrow = tid >> 3;               // 0..63
    const int gch  = (tid & 7) ^ (lrow & 7);
    const float*    Xbase = X  + (size_t)(m0  + lrow) * 4096 + gch * 8;
    const _Float16* Bbase = Wh + (size_t)(n0q + lrow) * 1024 + gch * 8;
    _Float16* AsSt = As + tid * 8;
    _Float16* BsSt = Bs + tid * 8;

    // fragment geometry (16x16x32): m/n = fr, k = kh*32 + qf*8 + j
    const int fr  = lane & 15;
    const int qf  = lane >> 4;
    const int fsw = fr & 7;
    const int sl0 = ((0 + qf) ^ fsw) * 8;    // kh=0 slot (halves)
    const int sl1 = ((4 + qf) ^ fsw) * 8;    // kh=1 slot
    const int arow = wmh * 4096 + fr * 64;   // within A quadrant region
    const int brow = broff + fr * 64;        // within B region

    // sign plan (R6/R7-proven): negseg boundary acc-flips + epilogue esign
    const int negseg = (comp == 0) ? 0 : (comp == 1) ? 3 : (comp == 2) ? 1 : 2;
    const int negFlipA = (negseg == 0) ? 16 : negseg * 16;
    const int negFlipB = (negseg == 0 || negseg == 3) ? -1 : negseg * 16 + 16;
    const float esign = (comp <= 1) ? -1.f : 1.f;

    floatx4 acc[8][4];
#pragma unroll
    for (int i = 0; i < 8; i++)
#pragma unroll
        for (int j = 0; j < 4; j++)
            acc[i][j] = (floatx4){0.f, 0.f, 0.f, 0.f};

    half8 af[4], bf0[4], bf1[4];
    float4 aS0, aS1, aS2, aS3, aS4, aS5, aS6, aS7;

    // ---- prologue: tile0 A (reg-staged) + B (DMA) into buf0
    AISSUE(0);
    STB(0, 0, 0); STB(1, 0, 0);
    WAITVM(4);                               // retires exactly A8(0)
    CVTWR(0);
    asm volatile("s_waitcnt lgkmcnt(0)" ::: "memory");  // drain ds_writes
    WAITVM(0);                               // retires B4(0)
    BAR;

    for (int tt = 0; tt < 64; ++tt) {
        const int cur = tt & 1, nxt = cur ^ 1;
        const _Float16* Acur = As + cur * 16384;
        const _Float16* Bcur = Bs + cur * 16384;
        const int t1 = (tt >= 63) ? 63 : tt + 1;

        // segment-boundary accumulator flip (<=2 per kernel, wave-uniform)
        if (tt == negFlipA || tt == negFlipB) {
#pragma unroll
            for (int i = 0; i < 8; i++)
#pragma unroll
                for (int j = 0; j < 4; j++)
                    acc[i][j] = -acc[i][j];
        }

        // ---- ph1: frags (g0,sl0)+B sl0; issue A8(t1)
        RDA(af, Acur, 0, sl0);
        RDB(bf0, Bcur, sl0);
        AISSUE(t1);
        WAITLGKM0;
        __builtin_amdgcn_s_setprio(1);
        MFMA16(0, af, bf0);
        __builtin_amdgcn_s_setprio(0);
        BAR;

        // ---- ph2: frags (g0,sl1)+B sl1; B-DMA(t1) -> nxt
        RDA(af, Acur, 0, sl1);
        RDB(bf1, Bcur, sl1);
        STB(0, t1, nxt);
        STB(1, t1, nxt);
        WAITLGKM0;
        __builtin_amdgcn_s_setprio(1);
        MFMA16(0, af, bf1);
        __builtin_amdgcn_s_setprio(0);
        BAR;

        // ---- ph3: frags (g1,sl0); A8 landed -> cvt + ds_write into nxt
        RDA(af, Acur, 1, sl0);
        WAITVM(4);                           // retires exactly A8(t1)
        CVTWR(nxt);
        WAITLGKM0;                           // drains reads AND writes
        __builtin_amdgcn_s_setprio(1);
        MFMA16(4, af, bf0);
        __builtin_amdgcn_s_setprio(0);
        BAR;

        // ---- ph4: frags (g1,sl1); drain B-DMA(t1) before publishing
        RDA(af, Acur, 1, sl1);
        WAITLGKM0;
        __builtin_amdgcn_s_setprio(1);
        MFMA16(4, af, bf1);
        __builtin_amdgcn_s_setprio(0);
        WAITVM(0);                           // retires exactly B4(t1)
        BAR;
    }

    // Epilogue: D[row][col], col = lane&15, row = (lane>>4)*4 + r  [m89 layout]
    const int col   = lane & 15;
    const int rquad = (lane >> 4) * 4;
    const int wm    = wmh * 128;
    const float* bsp[4] = {b0, b1, b2, b3};
#pragma unroll
    for (int j = 0; j < 4; j++) {
        const int gn = n0 + wn + j * 16 + col;
        const int o  = gn & 1023;
        float bv = 0.f;
#pragma unroll
        for (int c = 0; c < 4; c++)
            bv += d_stab[comp * 4 + c] * bsp[comp ^ c][o];
#pragma unroll
        for (int i = 0; i < 8; i++) {
            const int gmb = m0 + wm + i * 16 + rquad;
#pragma unroll
            for (int r = 0; r < 4; r++)
                C[(size_t)(gmb + r) * NDIM + gn] = esign * acc[i][j][r] + bv;
        }
    }
}

// ---------------- fp32 fallback (only if ws too small) ----------------
__global__ void fallback_kernel(const float* __restrict__ x,
                                const float* __restrict__ W0, const float* __restrict__ W1,
                                const float* __restrict__ W2, const float* __restrict__ W3,
                                const float* __restrict__ b0, const float* __restrict__ b1,
                                const float* __restrict__ b2, const float* __restrict__ b3,
                                float* __restrict__ out) {
    int idx = blockIdx.x * 256 + threadIdx.x;   // 16M outputs
    int m = idx >> 12, n = idx & 4095;
    int comp = n >> 10, o = n & 1023;
    const float* Ws[4] = {W0, W1, W2, W3};
    const float* bs[4] = {b0, b1, b2, b3};
    float acc = 0.f;
    for (int c = 0; c < 4; c++) {
        int t = comp * 4 + c;
        const float* wr = Ws[d_qtab[t]] + (size_t)o * 1024;
        const float* xr = x + (size_t)m * 4096 + c * 1024;
        float s = d_stab[t];
        float dot = 0.f;
        for (int i = 0; i < 1024; i += 4) {
            float4 wv = *(const float4*)(wr + i);
            float4 xv = *(const float4*)(xr + i);
            dot += wv.x * xv.x + wv.y * xv.y + wv.z * xv.z + wv.w * xv.w;
        }
        acc += s * dot + s * bs[d_qtab[t]][o];
    }
    out[idx] = acc;
}

// ---------------- launch ----------------
extern "C" void kernel_launch(void* const* d_in, const int* in_sizes, int n_in,
                              void* d_out, int out_size, void* d_ws, size_t ws_size,
                              hipStream_t stream) {
    const float* x = (const float*)d_in[0];
    const float* W[4];
    const float* b[4];
    int wi = 0, bi = 0;
    for (int i = 1; i < n_in && i < 9; i++) {
        if (in_sizes[i] > 4096) { if (wi < 4) W[wi++] = (const float*)d_in[i]; }
        else                    { if (bi < 4) b[bi++] = (const float*)d_in[i]; }
    }
    float* out = (float*)d_out;

    const size_t wh_elems = (size_t)4 * 1024 * 1024;    // 4M fp16 = 8 MB
    const size_t needed = wh_elems * 2;

    if (ws_size < needed) {
        fallback_kernel<<<(MDIM * NDIM) / 256, 256, 0, stream>>>(
            x, W[0], W[1], W[2], W[3], b[0], b[1], b[2], b[3], out);
        return;
    }

    _Float16* Wh = (_Float16*)d_ws;

    prepass_kernel<<<2048, 256, 0, stream>>>(W[0], W[1], W[2], W[3], Wh);
    gemm_kernel<<<(MDIM / 256) * (NDIM / 256), 512, 0, stream>>>(
        x, Wh, b[0], b[1], b[2], b[3], out);
}

// Round 9
// 283.993 us; speedup vs baseline: 1.0726x; 1.0726x over previous
//
#include <hip/hip_runtime.h>
#include <cstdint>
#include <cstddef>

#define MDIM 4096   // batch
#define NDIM 4096   // out features
#define KDIM 4096   // in features

typedef _Float16 half8   __attribute__((ext_vector_type(8)));
typedef float    floatx4 __attribute__((ext_vector_type(4)));

__device__ __constant__ int   d_qtab[16] = {0,1,2,3,  1,0,3,2,  2,3,0,1,  3,2,1,0};
__device__ __constant__ float d_stab[16] = {1.f,-1.f,-1.f,-1.f,
                                            1.f, 1.f, 1.f,-1.f,
                                            1.f,-1.f, 1.f, 1.f,
                                            1.f, 1.f,-1.f, 1.f};

__device__ __forceinline__ half8 cvt8(float4 a, float4 b) {
    return (half8){(_Float16)a.x, (_Float16)a.y, (_Float16)a.z, (_Float16)a.w,
                   (_Float16)b.x, (_Float16)b.y, (_Float16)b.z, (_Float16)b.w};
}

// ---- prepass: cast x -> fp16 (blocks 0..8191); W -> fragment-major fp16 Wt ---
// Wt layout (halves): [(((w*16+nb)*16+tl)*2+kh)*4+j][lane][8]
//   n = nb*64 + j*16 + (lane&15), k = tl*64 + kh*32 + (lane>>4)*8 + e.
// A B-fragment load in the gemm = Wt + frag_idx*512 + lane*8: one contiguous
// 1 KB per-wave read (this is what R6's direct-B lacked -- its loads touched
// 64 cache lines each). Coalesced source reads (32 B/thread along k).
__global__ void prepass_kernel(const float* __restrict__ x,
                               const float* __restrict__ W0, const float* __restrict__ W1,
                               const float* __restrict__ W2, const float* __restrict__ W3,
                               _Float16* __restrict__ xh, _Float16* __restrict__ Wt) {
    int b = blockIdx.x;
    if (b < 8192) {
        int idx = b * 256 + threadIdx.x;               // 0 .. 2M-1
        const float4* src = (const float4*)x + (size_t)idx * 2;
        float4 a = src[0], v = src[1];
        ((half8*)xh)[idx] = cvt8(a, v);
    } else {
        int idx = (b - 8192) * 256 + threadIdx.x;      // 0 .. 512K-1
        int w  = idx >> 17;                            // source matrix 0..3
        int r  = idx & 131071;
        int n  = r >> 7;                               // 0..1023
        int kc = r & 127;                              // k chunk (8 halves)
        const float* Ws[4] = {W0, W1, W2, W3};
        const float* src = Ws[w] + (size_t)n * 1024 + kc * 8;
        float4 a = *(const float4*)src;
        float4 v = *(const float4*)(src + 4);
        int nb = n >> 6, j = (n >> 4) & 3, fr = n & 15;
        int tl = kc >> 3, kh = (kc >> 2) & 1, qf = kc & 3;
        int lane = qf * 16 + fr;
        size_t off = (size_t)(((((w * 16 + nb) * 16 + tl) * 2 + kh) * 4 + j)) * 512
                   + lane * 8;
        *(half8*)(Wt + off) = cvt8(a, v);
    }
}

// --- MFMA GEMM: 256x256, BK=64, 8 waves; A via LDS (fp16 DMA), B direct ------
// from fragment-major Wt (L2/L3-resident, contiguous 1KB wave-loads).
// LDS-pipe demand per tile drops 2800 -> ~1790 cyc (< MFMA 2480): A-only
// reads 16 b128/thread + 2KB DMA-writes. Compute phases verbatim R3/R4.
// vmcnt ledger (per-wave FIFO, robust to intra-phase reorder):
//   ph4(t-1): issue bf0(t)      -> WAITVM(4) keeps them in flight
//   ph1(t):   issue bf1(t), A4(t+1)  [queue: bf0 4 | bf1 4 | A4 4]
//     ph1 MFMA: compiler waits bf0 (vmcnt<=8)
//     ph2 MFMA: compiler waits bf1 (vmcnt<=4; A4 newer, stays)
//   ph4(t): LDB bf0(t+1); MFMA (regs only); WAITVM(4) retires A4(t+1),
//     keeps bf0(t+1). ph4-end BAR publishes A(t+1) for ph1(t+1) reads.
// All A-region WAR windows: nxt's last ds-reads were t-1 ph3/ph4, drained by
// their lgkm0 >= 2 BARs before ph1(t)'s DMA issue.
// Tail: t1 clamps to 63 (dead restage + dead bf0 reload, ledger invariant).
// Signs (R6/R7-proven): acc flip at negseg boundaries + epilogue esign.
// LDS: rows of 64 halves (128B), slot = chunk ^ (row&7) (0 conflicts measured).

__device__ __forceinline__ void gload_lds16(const _Float16* g, _Float16* l) {
    __builtin_amdgcn_global_load_lds(
        (const __attribute__((address_space(1))) unsigned int*)g,
        (__attribute__((address_space(3))) unsigned int*)l,
        16, 0, 0);
}

#define BAR __builtin_amdgcn_s_barrier()
#define SCHEDB __builtin_amdgcn_sched_barrier(0)
#define WAITVM(N) asm volatile("s_waitcnt vmcnt(" #N ")" ::: "memory")
#define WAITLGKM0 do { asm volatile("s_waitcnt lgkmcnt(0)" ::: "memory"); \
                       SCHEDB; } while (0)

// stage A tile tt (256 rows x 64 k, fp16) into buffer buf: 4 DMA issues,
// issue rg covers rows rg*64 + lrow
#define STA4(tt, buf) { \
    const _Float16* _s = Abase + (tt) * 64; \
    _Float16* _d = AsSt + (buf) * 16384; \
    gload_lds16(_s,                          _d); \
    gload_lds16(_s + (size_t) 64 * 4096,     _d + 4096); \
    gload_lds16(_s + (size_t)128 * 4096,     _d + 8192); \
    gload_lds16(_s + (size_t)192 * 4096,     _d + 12288); }

// B fragments for k-half KH from fragment-major Wt (base Wtb, per tile)
#define LDB(BQ, WTB, KH) { \
    const _Float16* _p = (WTB) + (KH) * 2048; \
    BQ[0] = *(const half8*)(_p); \
    BQ[1] = *(const half8*)(_p + 512); \
    BQ[2] = *(const half8*)(_p + 1024); \
    BQ[3] = *(const half8*)(_p + 1536); }

// A fragments: region rg (64 rows), frag rows (i&3)*16 + fr, slot SL
#define RDA(AF, BASE, rg, SL) { \
    const _Float16* _p = (BASE) + (rg) * 4096 + fr * 64 + (SL); \
    AF[0] = *(const half8*)(_p); \
    AF[1] = *(const half8*)(_p + 1024); \
    AF[2] = *(const half8*)(_p + 2048); \
    AF[3] = *(const half8*)(_p + 3072); }

#define MFMA16(IB, AF, BQ) \
    _Pragma("unroll") \
    for (int _i = 0; _i < 4; _i++) \
      _Pragma("unroll") \
      for (int _j = 0; _j < 4; _j++) \
        acc[(IB) + _i][_j] = __builtin_amdgcn_mfma_f32_16x16x32_f16( \
            AF[_i], BQ[_j], acc[(IB) + _i][_j], 0, 0, 0);

__global__ __launch_bounds__(512, 2) void gemm_kernel(
        const _Float16* __restrict__ A,      // xh [4096,4096] fp16
        const _Float16* __restrict__ Wt,     // fragment-major W, 4M halves
        const float* __restrict__ b0, const float* __restrict__ b1,
        const float* __restrict__ b2, const float* __restrict__ b3,
        float* __restrict__ C) {
    __shared__ _Float16 As[32768];           // 64 KiB: A only, [buf][16384]

    const int tid  = threadIdx.x;
    const int lane = tid & 63;
    const int wave = tid >> 6;               // 0..7
    const int wmh  = wave >> 2;              // M-half (0/1)
    const int wn   = (wave & 3) * 64;        // N offset within 256-col tile

    // bijective XCD swizzle (nwg=256): each XCD gets 2 full bm-rows
    const int wg = ((blockIdx.x & 7) << 5) | (blockIdx.x >> 3);
    const int bm = wg >> 4, bn = wg & 15;
    const int m0 = bm << 8;
    const int n0 = bn << 8;
    const int comp = bn >> 2;
    const int n0q  = n0 & 1023;
    const int nb   = (n0q + wn) >> 6;        // B fragment-major n-block 0..15

    // A staging geometry: 8 threads/row over 64 rows, 16B chunks,
    // slot s holds chunk s^(row&7)
    const int lrow = tid >> 3;               // 0..63
    const int gch  = (tid & 7) ^ (lrow & 7);
    const _Float16* Abase = A + (size_t)(m0 + lrow) * 4096 + gch * 8;
    _Float16* AsSt = As + tid * 8;

    // fragment geometry (16x16x32): m/n = fr, k = kh*32 + qf*8 + j
    const int fr  = lane & 15;
    const int qf  = lane >> 4;
    const int fsw = fr & 7;
    const int sl0 = ((0 + qf) ^ fsw) * 8;
    const int sl1 = ((4 + qf) ^ fsw) * 8;
    const int rg0 = wmh * 2;                 // A regions for this wave
    const int rg1 = wmh * 2 + 1;

    // sign plan (R6/R7-proven)
    const int negseg = (comp == 0) ? 0 : (comp == 1) ? 3 : (comp == 2) ? 1 : 2;
    const int negFlipA = (negseg == 0) ? 16 : negseg * 16;
    const int negFlipB = (negseg == 0 || negseg == 3) ? -1 : negseg * 16 + 16;
    const float esign = (comp <= 1) ? -1.f : 1.f;

    floatx4 acc[8][4];
#pragma unroll
    for (int i = 0; i < 8; i++)
#pragma unroll
        for (int j = 0; j < 4; j++)
            acc[i][j] = (floatx4){0.f, 0.f, 0.f, 0.f};

    half8 af[4], bf0[4], bf1[4];

    // per-tile Wt base: w = comp^(tt>>4), tl = tt&15
    const _Float16* WtL = Wt + lane * 8;
#define WTB(TT) (WtL + (size_t)(((comp ^ ((TT) >> 4)) * 16 + nb) * 16 + ((TT) & 15)) * 4096)

    // ---- prologue: A(0) -> buf0; bf0(0) issued after (stays in flight)
    STA4(0, 0);
    LDB(bf0, WTB(0), 0);
    WAITVM(4);                               // retires A4(0), keeps bf0(0)
    BAR;

    for (int tt = 0; tt < 64; ++tt) {
        const int cur = tt & 1, nxt = cur ^ 1;
        const _Float16* Acur = As + cur * 16384;
        const int t1 = (tt >= 63) ? 63 : tt + 1;
        const _Float16* Wtb  = WTB(tt);

        if (tt == negFlipA || tt == negFlipB) {
#pragma unroll
            for (int i = 0; i < 8; i++)
#pragma unroll
                for (int j = 0; j < 4; j++)
                    acc[i][j] = -acc[i][j];
        }

        // ---- ph1: frags (rg0,sl0); issue bf1(tt) then A4(t1)->nxt
        RDA(af, Acur, rg0, sl0);
        LDB(bf1, Wtb, 1);
        SCHEDB;                              // keep bf1 issue before A-DMA
        STA4(t1, nxt);                       // nxt's last reads: t-1 ph3/ph4
        WAITLGKM0;
        __builtin_amdgcn_s_setprio(1);
        MFMA16(0, af, bf0);                  // compiler waits bf0 (vmcnt<=8)
        __builtin_amdgcn_s_setprio(0);
        BAR;

        // ---- ph2: frags (rg0,sl1)
        RDA(af, Acur, rg0, sl1);
        WAITLGKM0;
        __builtin_amdgcn_s_setprio(1);
        MFMA16(0, af, bf1);                  // compiler waits bf1 (vmcnt<=4)
        __builtin_amdgcn_s_setprio(0);
        BAR;

        // ---- ph3: frags (rg1,sl0); bf0 reused from regs
        RDA(af, Acur, rg1, sl0);
        WAITLGKM0;
        __builtin_amdgcn_s_setprio(1);
        MFMA16(4, af, bf0);
        __builtin_amdgcn_s_setprio(0);
        BAR;

        // ---- ph4: frags (rg1,sl1); prefetch bf0(t1); counted vm retire
        RDA(af, Acur, rg1, sl1);
        LDB(bf0, WTB(t1), 0);
        WAITLGKM0;
        __builtin_amdgcn_s_setprio(1);
        MFMA16(4, af, bf1);
        __builtin_amdgcn_s_setprio(0);
        WAITVM(4);                           // retires A4(t1); keeps bf0(t1)
        BAR;
    }

    WAITVM(0);   // drain tail DMAs

    // Epilogue: D[row][col], col = lane&15, row = (lane>>4)*4 + r  [m89 layout]
    const int col   = lane & 15;
    const int rquad = (lane >> 4) * 4;
    const int wm    = wmh * 128;
    const float* bsp[4] = {b0, b1, b2, b3};
#pragma unroll
    for (int j = 0; j < 4; j++) {
        const int gn = n0 + wn + j * 16 + col;
        const int o  = gn & 1023;
        float bv = 0.f;
#pragma unroll
        for (int c = 0; c < 4; c++)
            bv += d_stab[comp * 4 + c] * bsp[comp ^ c][o];
#pragma unroll
        for (int i = 0; i < 8; i++) {
            const int gmb = m0 + wm + i * 16 + rquad;
#pragma unroll
            for (int r = 0; r < 4; r++)
                C[(size_t)(gmb + r) * NDIM + gn] = esign * acc[i][j][r] + bv;
        }
    }
}

// ---------------- fp32 fallback (only if ws too small) ----------------
__global__ void fallback_kernel(const float* __restrict__ x,
                                const float* __restrict__ W0, const float* __restrict__ W1,
                                const float* __restrict__ W2, const float* __restrict__ W3,
                                const float* __restrict__ b0, const float* __restrict__ b1,
                                const float* __restrict__ b2, const float* __restrict__ b3,
                                float* __restrict__ out) {
    int idx = blockIdx.x * 256 + threadIdx.x;   // 16M outputs
    int m = idx >> 12, n = idx & 4095;
    int comp = n >> 10, o = n & 1023;
    const float* Ws[4] = {W0, W1, W2, W3};
    const float* bs[4] = {b0, b1, b2, b3};
    float acc = 0.f;
    for (int c = 0; c < 4; c++) {
        int t = comp * 4 + c;
        const float* wr = Ws[d_qtab[t]] + (size_t)o * 1024;
        const float* xr = x + (size_t)m * 4096 + c * 1024;
        float s = d_stab[t];
        float dot = 0.f;
        for (int i = 0; i < 1024; i += 4) {
            float4 wv = *(const float4*)(wr + i);
            float4 xv = *(const float4*)(xr + i);
            dot += wv.x * xv.x + wv.y * xv.y + wv.z * xv.z + wv.w * xv.w;
        }
        acc += s * dot + s * bs[d_qtab[t]][o];
    }
    out[idx] = acc;
}

// ---------------- launch ----------------
extern "C" void kernel_launch(void* const* d_in, const int* in_sizes, int n_in,
                              void* d_out, int out_size, void* d_ws, size_t ws_size,
                              hipStream_t stream) {
    const float* x = (const float*)d_in[0];
    const float* W[4];
    const float* b[4];
    int wi = 0, bi = 0;
    for (int i = 1; i < n_in && i < 9; i++) {
        if (in_sizes[i] > 4096) { if (wi < 4) W[wi++] = (const float*)d_in[i]; }
        else                    { if (bi < 4) b[bi++] = (const float*)d_in[i]; }
    }
    float* out = (float*)d_out;

    const size_t xh_elems = (size_t)MDIM * KDIM;        // 16M fp16 = 32 MB
    const size_t wt_elems = (size_t)4 * 1024 * 1024;    // 4M fp16 = 8 MB
    const size_t needed = (xh_elems + wt_elems) * 2;

    if (ws_size < needed) {
        fallback_kernel<<<(MDIM * NDIM) / 256, 256, 0, stream>>>(
            x, W[0], W[1], W[2], W[3], b[0], b[1], b[2], b[3], out);
        return;
    }

    _Float16* xh = (_Float16*)d_ws;
    _Float16* Wt = xh + xh_elems;

    prepass_kernel<<<8192 + 2048, 256, 0, stream>>>(x, W[0], W[1], W[2], W[3], xh, Wt);
    gemm_kernel<<<(MDIM / 256) * (NDIM / 256), 512, 0, stream>>>(
        xh, Wt, b[0], b[1], b[2], b[3], out);
}

// Round 10
// 258.658 us; speedup vs baseline: 1.1776x; 1.0979x over previous
//
#include <hip/hip_runtime.h>
#include <cstdint>
#include <cstddef>

#define MDIM 4096   // batch
#define NDIM 4096   // out features
#define KDIM 4096   // in features

typedef _Float16 half8   __attribute__((ext_vector_type(8)));
typedef float    floatx4 __attribute__((ext_vector_type(4)));

// Hamilton product tables: out_comp = sum_c sign[comp][c] * (x_c @ W_{comp^c}^T)
__device__ __constant__ int   d_qtab[16] = {0,1,2,3,  1,0,3,2,  2,3,0,1,  3,2,1,0};
__device__ __constant__ float d_stab[16] = {1.f,-1.f,-1.f,-1.f,
                                            1.f, 1.f, 1.f,-1.f,
                                            1.f,-1.f, 1.f, 1.f,
                                            1.f, 1.f,-1.f, 1.f};

// ---------------- fused pre-pass: cast x -> fp16, cast W -> fp16 ----------------
__global__ void prepass_kernel(const float* __restrict__ x,
                               const float* __restrict__ W0, const float* __restrict__ W1,
                               const float* __restrict__ W2, const float* __restrict__ W3,
                               _Float16* __restrict__ xh, _Float16* __restrict__ Wh) {
    int b = blockIdx.x;
    if (b < 8192) {
        int idx = b * 256 + threadIdx.x;               // 0 .. 2M-1
        const float4* src = (const float4*)x + (size_t)idx * 2;
        float4 a = src[0], v = src[1];
        half8 h = {(_Float16)a.x, (_Float16)a.y, (_Float16)a.z, (_Float16)a.w,
                   (_Float16)v.x, (_Float16)v.y, (_Float16)v.z, (_Float16)v.w};
        ((half8*)xh)[idx] = h;
    } else {
        int idx = (b - 8192) * 256 + threadIdx.x;      // 0 .. 512K-1
        int e = idx << 3;                               // 0 .. 4M-1
        int m = e >> 20;
        int off = e & ((1 << 20) - 1);
        const float* Ws[4] = {W0, W1, W2, W3};
        const float* src = Ws[m] + off;
        float4 a = *(const float4*)src;
        float4 v = *(const float4*)(src + 4);
        half8 h = {(_Float16)a.x, (_Float16)a.y, (_Float16)a.z, (_Float16)a.w,
                   (_Float16)v.x, (_Float16)v.y, (_Float16)v.z, (_Float16)v.w};
        *(half8*)(Wh + ((size_t)m << 20) + off) = h;
    }
}

// ---------------- MFMA GEMM: 256x256 tile, BK=64, 8 waves, 4-phase pipeline ----
// Session-best structure (measured 135us gemm / 254us total, MfmaUtil 46%).
// Per-phase: {ds_read; stage-issue; lgkmcnt(0)+sched_barrier; MFMA; [vm]; BAR}.
// Each wave's lgkmcnt(0) precedes its MFMA which precedes the phase-end
// barrier, so by any phase-end barrier ALL waves' reads of the regions
// overwritten in later phases have drained; region-reads follow the barrier
// after the counted WAITVM that landed them.
// Staging schedule per tile t (cur=t&1, nxt=cur^1):
//   ph1: Bn1(t+1)->nxt   ph2: Ag1(t+1)->nxt   ph3: Ag0(t+2)->cur   ph4: Bn0(t+2)->cur
// Counted waits (2 loads per half-tile, per wave):
//   ph2: vmcnt(8)  -- lands Ag1(t)  [issued t-1 ph2], needed ph3
//   ph4: vmcnt(6)  -- lands Ag0/Bn0/Bn1(t+1), leaves 3 half-tiles in flight
// Never vmcnt(0) in the loop. Tail: t1/t2 clamped to 63 (re-stage same data
// into dead regions) so the vmcnt ledger is identical every iteration.
// LDS geometry per region: rows of 64 halves (128 B), slot = chunk ^ (row&7)
// (0 bank conflicts measured in R0/R1/R3/R4/R7).
// Failed alternatives (measured this session): lockstep pre-MFMA barrier
// (-10%), reg-prefetch ping-pong (neutral), m201 12/4/8/4 composition (-7%),
// B direct-from-global scattered (-60%) and fragment-major (-24%, L2-path
// 56B/cyc/CU < LDS 112B/cyc), fused fp32 A-staging (-62%).

__device__ __forceinline__ void gload_lds16(const _Float16* g, _Float16* l) {
    __builtin_amdgcn_global_load_lds(
        (const __attribute__((address_space(1))) unsigned int*)g,
        (__attribute__((address_space(3))) unsigned int*)l,
        16, 0, 0);
}

#define BAR __builtin_amdgcn_s_barrier()
#define WAITLGKM do { asm volatile("s_waitcnt lgkmcnt(0)" ::: "memory"); \
                      __builtin_amdgcn_sched_barrier(0); } while (0)
#define WAITVM(N) asm volatile("s_waitcnt vmcnt(" #N ")" ::: "memory")

// stage A quadrant-half g of K-tile tt into buffer buf (2 x 64 rows)
#define STA(g, tt, buf) { \
    const _Float16* _s = Abase + (size_t)((g) * 64) * KDIM + (tt) * 64; \
    _Float16* _d = AsSt + (buf) * 16384 + (g) * 8192; \
    gload_lds16(_s, _d); \
    gload_lds16(_s + (size_t)128 * KDIM, _d + 4096); }

// stage B n-half h of K-tile tt into buffer buf
#define STB(h, tt, buf) { \
    const int _sg = (tt) >> 4; \
    const _Float16* _s = Bbase + ((size_t)(comp ^ _sg) << 20) \
                       + (size_t)((h) * 128) * 1024 + ((tt) & 15) * 64; \
    _Float16* _d = BsSt + (buf) * 16384 + (h) * 8192; \
    gload_lds16(_s, _d); \
    gload_lds16(_s + 64 * 1024, _d + 4096); }

#define RDA(g, SL) { \
    const _Float16* _p = Acur + (g) * 8192 + arow + (SL); \
    af[0] = *(const half8*)(_p); \
    af[1] = *(const half8*)(_p + 1024); \
    af[2] = *(const half8*)(_p + 2048); \
    af[3] = *(const half8*)(_p + 3072); }

#define RDB(BQ, SL) { \
    const _Float16* _p = Bcur + bnh * 8192 + brow + (SL); \
    BQ[0] = *(const half8*)(_p); \
    BQ[1] = *(const half8*)(_p + 1024); \
    BQ[2] = *(const half8*)(_p + 2048); \
    BQ[3] = *(const half8*)(_p + 3072); \
    if (bneg) { BQ[0] = -BQ[0]; BQ[1] = -BQ[1]; BQ[2] = -BQ[2]; BQ[3] = -BQ[3]; } }

#define MFMA16(IB, BQ) \
    _Pragma("unroll") \
    for (int _i = 0; _i < 4; _i++) \
      _Pragma("unroll") \
      for (int _j = 0; _j < 4; _j++) \
        acc[(IB) + _i][_j] = __builtin_amdgcn_mfma_f32_16x16x32_f16( \
            af[_i], BQ[_j], acc[(IB) + _i][_j], 0, 0, 0);

__global__ __launch_bounds__(512, 2) void gemm_kernel(
        const _Float16* __restrict__ A,      // [4096,4096] fp16
        const _Float16* __restrict__ Wh,     // [4][1024][1024] fp16
        const float* __restrict__ b0, const float* __restrict__ b1,
        const float* __restrict__ b2, const float* __restrict__ b3,
        float* __restrict__ C) {
    __shared__ _Float16 lds[65536];          // 128 KiB
    _Float16* As = lds;                      // [buf][g][8192]
    _Float16* Bs = lds + 32768;              // [buf][nh][8192]

    const int tid  = threadIdx.x;
    const int lane = tid & 63;
    const int wave = tid >> 6;               // 0..7
    const int wmh  = wave >> 2;              // M-half of 256-row tile (0/1)
    const int wn   = (wave & 3) * 64;        // N offset within 256-col tile
    const int bnh  = wn >> 7;                // which B region this wave reads
    const int broff = (wn & 64) * 64;        // row base (halves) within B region

    // bijective XCD swizzle (nwg=256 divisible by 8): each XCD gets 2 full
    // bm-rows (all 16 bn) -> A panels L2-local per XCD.
    const int wg = ((blockIdx.x & 7) << 5) | (blockIdx.x >> 3);
    const int bm = wg >> 4, bn = wg & 15;
    const int m0 = bm << 8;
    const int n0 = bn << 8;
    const int comp = bn >> 2;                // output quaternion component
    const int n0q  = n0 & 1023;

    // staging geometry: 8 threads/row, 16B chunks, slot s holds chunk s^(row&7)
    const int lrow = tid >> 3;               // 0..63
    const int gch  = (tid & 7) ^ (lrow & 7);
    const _Float16* Abase = A  + (size_t)(m0  + lrow) * KDIM + gch * 8;
    const _Float16* Bbase = Wh + (size_t)(n0q + lrow) * 1024 + gch * 8;
    _Float16* AsSt = As + tid * 8;
    _Float16* BsSt = Bs + tid * 8;

    // fragment geometry (16x16x32): m/n = fr, k = kh*32 + qf*8 + j
    const int fr  = lane & 15;
    const int qf  = lane >> 4;
    const int fsw = fr & 7;
    const int sl0 = ((0 + qf) ^ fsw) * 8;    // kh=0 slot (halves)
    const int sl1 = ((4 + qf) ^ fsw) * 8;    // kh=1 slot
    const int arow = wmh * 4096 + fr * 64;   // within A quadrant region
    const int brow = broff + fr * 64;        // within B n-half region

    // signs: one negated segment per comp + global flip (comp0 only)
    const int negseg = (comp == 0) ? 0 : (comp == 1) ? 3 : (comp == 2) ? 1 : 2;
    const float flip = (comp == 0) ? -1.f : 1.f;

    floatx4 acc[8][4];
#pragma unroll
    for (int i = 0; i < 8; i++)
#pragma unroll
        for (int j = 0; j < 4; j++)
            acc[i][j] = (floatx4){0.f, 0.f, 0.f, 0.f};

    // ---- prologue: tile0 fully + Ag0/Bn0 of tile1; leave 3 half-tiles in flight
    STA(0, 0, 0); STB(0, 0, 0); STB(1, 0, 0); STA(1, 0, 0);
    STA(0, 1, 1); STB(0, 1, 1);
    WAITVM(6);                               // lands Ag0/Bn0/Bn1 of tile 0
    BAR;

    for (int tt = 0; tt < 64; ++tt) {
        const int cur = tt & 1, nxt = cur ^ 1;
        const bool bneg = ((tt >> 4) == negseg);
        const _Float16* Acur = As + cur * 16384;
        const _Float16* Bcur = Bs + cur * 16384;
        const int t1 = (tt >= 63) ? 63 : tt + 1;
        const int t2 = (tt >= 62) ? 63 : tt + 2;
        half8 af[4], bf0[4], bf1[4];

        // ---- phase 1: quad(g0,kh0), load+scale bf0; prefetch Bn1(t+1)
        RDA(0, sl0); RDB(bf0, sl0);
        STB(1, t1, nxt);
        WAITLGKM;
        __builtin_amdgcn_s_setprio(1);
        MFMA16(0, bf0);
        __builtin_amdgcn_s_setprio(0);
        BAR;

        // ---- phase 2: quad(g0,kh1), load+scale bf1; prefetch Ag1(t+1)
        RDA(0, sl1); RDB(bf1, sl1);
        STA(1, t1, nxt);
        WAITLGKM;
        __builtin_amdgcn_s_setprio(1);
        MFMA16(0, bf1);
        __builtin_amdgcn_s_setprio(0);
        WAITVM(8);                           // lands Ag1(tt) for phase 3
        BAR;

        // ---- phase 3: quad(g1,kh0), reuse bf0; prefetch Ag0(t+2) into cur
        RDA(1, sl0);
        STA(0, t2, cur);                     // region freed: all reads drained
        WAITLGKM;                            //   before each wave's ph2 MFMA < BAR
        __builtin_amdgcn_s_setprio(1);
        MFMA16(4, bf0);
        __builtin_amdgcn_s_setprio(0);
        BAR;

        // ---- phase 4: quad(g1,kh1), reuse bf1; prefetch Bn0(t+2) into cur
        RDA(1, sl1);
        STB(0, t2, cur);
        WAITLGKM;
        __builtin_amdgcn_s_setprio(1);
        MFMA16(4, bf1);
        __builtin_amdgcn_s_setprio(0);
        WAITVM(6);                           // lands tile t+1's ph1/ph2 needs
        BAR;
    }

    WAITVM(0);   // drain tail DMAs before LDS teardown

    // Epilogue: D[row][col], col = lane&15, row = (lane>>4)*4 + r  [m89 layout]
    const int col   = lane & 15;
    const int rquad = (lane >> 4) * 4;
    const int wm    = wmh * 128;
    const float* bsp[4] = {b0, b1, b2, b3};
#pragma unroll
    for (int j = 0; j < 4; j++) {
        const int gn = n0 + wn + j * 16 + col;
        const int o  = gn & 1023;
        float bv = 0.f;
#pragma unroll
        for (int c = 0; c < 4; c++)
            bv += d_stab[comp * 4 + c] * bsp[comp ^ c][o];
#pragma unroll
        for (int i = 0; i < 8; i++) {
            const int gmb = m0 + wm + i * 16 + rquad;
#pragma unroll
            for (int r = 0; r < 4; r++)
                C[(size_t)(gmb + r) * NDIM + gn] = flip * acc[i][j][r] + bv;
        }
    }
}

// ---------------- fp32 fallback (only if ws too small) ----------------
__global__ void fallback_kernel(const float* __restrict__ x,
                                const float* __restrict__ W0, const float* __restrict__ W1,
                                const float* __restrict__ W2, const float* __restrict__ W3,
                                const float* __restrict__ b0, const float* __restrict__ b1,
                                const float* __restrict__ b2, const float* __restrict__ b3,
                                float* __restrict__ out) {
    int idx = blockIdx.x * 256 + threadIdx.x;   // 16M outputs
    int m = idx >> 12, n = idx & 4095;
    int comp = n >> 10, o = n & 1023;
    const float* Ws[4] = {W0, W1, W2, W3};
    const float* bs[4] = {b0, b1, b2, b3};
    float acc = 0.f;
    for (int c = 0; c < 4; c++) {
        int t = comp * 4 + c;
        const float* wr = Ws[d_qtab[t]] + (size_t)o * 1024;
        const float* xr = x + (size_t)m * 4096 + c * 1024;
        float s = d_stab[t];
        float dot = 0.f;
        for (int i = 0; i < 1024; i += 4) {
            float4 wv = *(const float4*)(wr + i);
            float4 xv = *(const float4*)(xr + i);
            dot += wv.x * xv.x + wv.y * xv.y + wv.z * xv.z + wv.w * xv.w;
        }
        acc += s * dot + s * bs[d_qtab[t]][o];
    }
    out[idx] = acc;
}

// ---------------- launch ----------------
extern "C" void kernel_launch(void* const* d_in, const int* in_sizes, int n_in,
                              void* d_out, int out_size, void* d_ws, size_t ws_size,
                              hipStream_t stream) {
    const float* x = (const float*)d_in[0];
    const float* W[4];
    const float* b[4];
    int wi = 0, bi = 0;
    for (int i = 1; i < n_in && i < 9; i++) {
        if (in_sizes[i] > 4096) { if (wi < 4) W[wi++] = (const float*)d_in[i]; }
        else                    { if (bi < 4) b[bi++] = (const float*)d_in[i]; }
    }
    float* out = (float*)d_out;

    const size_t xh_elems = (size_t)MDIM * KDIM;        // 16M fp16 = 32 MB
    const size_t wh_elems = (size_t)4 * 1024 * 1024;    // 4M fp16 = 8 MB
    const size_t needed = (xh_elems + wh_elems) * 2;

    if (ws_size < needed) {
        fallback_kernel<<<(MDIM * NDIM) / 256, 256, 0, stream>>>(
            x, W[0], W[1], W[2], W[3], b[0], b[1], b[2], b[3], out);
        return;
    }

    _Float16* xh = (_Float16*)d_ws;
    _Float16* Wh = xh + xh_elems;

    prepass_kernel<<<8192 + 2048, 256, 0, stream>>>(x, W[0], W[1], W[2], W[3], xh, Wh);
    gemm_kernel<<<(MDIM / 256) * (NDIM / 256), 512, 0, stream>>>(
        xh, Wh, b[0], b[1], b[2], b[3], out);
}

// Round 11
// 254.474 us; speedup vs baseline: 1.1970x; 1.0164x over previous
//
#include <hip/hip_runtime.h>
#include <cstdint>
#include <cstddef>

#define MDIM 4096   // batch
#define NDIM 4096   // out features
#define KDIM 4096   // in features

typedef _Float16 half8   __attribute__((ext_vector_type(8)));
typedef float    floatx4 __attribute__((ext_vector_type(4)));

// Hamilton product tables: out_comp = sum_c sign[comp][c] * (x_c @ W_{comp^c}^T)
__device__ __constant__ int   d_qtab[16] = {0,1,2,3,  1,0,3,2,  2,3,0,1,  3,2,1,0};
__device__ __constant__ float d_stab[16] = {1.f,-1.f,-1.f,-1.f,
                                            1.f, 1.f, 1.f,-1.f,
                                            1.f,-1.f, 1.f, 1.f,
                                            1.f, 1.f,-1.f, 1.f};

// ---------------- fused pre-pass: cast x -> fp16, cast W -> fp16 ----------------
__global__ void prepass_kernel(const float* __restrict__ x,
                               const float* __restrict__ W0, const float* __restrict__ W1,
                               const float* __restrict__ W2, const float* __restrict__ W3,
                               _Float16* __restrict__ xh, _Float16* __restrict__ Wh) {
    int b = blockIdx.x;
    if (b < 8192) {
        int idx = b * 256 + threadIdx.x;               // 0 .. 2M-1
        const float4* src = (const float4*)x + (size_t)idx * 2;
        float4 a = src[0], v = src[1];
        half8 h = {(_Float16)a.x, (_Float16)a.y, (_Float16)a.z, (_Float16)a.w,
                   (_Float16)v.x, (_Float16)v.y, (_Float16)v.z, (_Float16)v.w};
        ((half8*)xh)[idx] = h;
    } else {
        int idx = (b - 8192) * 256 + threadIdx.x;      // 0 .. 512K-1
        int e = idx << 3;                               // 0 .. 4M-1
        int m = e >> 20;
        int off = e & ((1 << 20) - 1);
        const float* Ws[4] = {W0, W1, W2, W3};
        const float* src = Ws[m] + off;
        float4 a = *(const float4*)src;
        float4 v = *(const float4*)(src + 4);
        half8 h = {(_Float16)a.x, (_Float16)a.y, (_Float16)a.z, (_Float16)a.w,
                   (_Float16)v.x, (_Float16)v.y, (_Float16)v.z, (_Float16)v.w};
        *(half8*)(Wh + ((size_t)m << 20) + off) = h;
    }
}

// ------- MFMA GEMM: 256x256 tile, BK=64, 8 waves, 4-phase + reg prefetch -------
// SESSION-FINAL kernel: best-measured gemm dispatch (132.6us, MfmaUtil 46%).
// Fragments for phase p are ds_read during phase p-1 into ping-pong register
// sets (afP/afQ for A, bf0/bf1 for B), consumed with the compiler's COUNTED
// lgkm wait (no manual lgkmcnt(0) drain before MFMA). sched_barrier(0) pins
// {reads, stage} above each MFMA cluster.
//
// Cross-wave DMA visibility: every prefetch read that consumes DMA'd data sits
// one BARRIER after the counted WAITVM that retires it (vm-wait at phase END,
// read in the NEXT phase) -- a wave's vmcnt only covers its OWN DMAs, so the
// barrier is what publishes all waves' slices.
//   ph1-end: WAITVM(6)  -- lands Ag1(t)            (read by ph2's prefetch)
//   ph3-end: WAITVM(4)  -- lands Ag0/Bn0/Bn1(t+1)  (read by ph4's prefetch)
// Staging schedule per tile t (cur=t&1, nxt=cur^1):
//   ph1: Bn1(t+1)->nxt  ph2: Ag1(t+1)->nxt  ph3: Ag0(t+2)->cur  ph4: Bn0(t+2)->cur
// LDS WAR windows all retain a >=1-barrier gap (reads of a region retire at the
// consuming MFMA's lgkm wait, >=1 BAR before the overwriting DMA issues).
// Tail: t1/t2 clamped to 63 so the vmcnt ledger shape is loop-invariant.
// LDS geometry per region: rows of 64 halves (128 B), slot = chunk ^ (row&7)
// (0 bank conflicts measured across all rounds).
//
// Measured alternatives (10-round session): lockstep pre-MFMA barrier -10%;
// m201 12/4/8/4 quadrant composition -7%; B direct-from-global scattered -60%;
// B fragment-major direct -24% (L2 path 56 B/cyc/CU < LDS 112 B/cyc/CU);
// fused fp32 A-staging -62%. The 46% plateau is the sum-serialization of
// MFMA (~2480 cyc/tile/CU) + LDS pipe (~2300 cyc) + DMA, which plain-HIP
// scheduling could not convert to max() in 7 attempts.

__device__ __forceinline__ void gload_lds16(const _Float16* g, _Float16* l) {
    __builtin_amdgcn_global_load_lds(
        (const __attribute__((address_space(1))) unsigned int*)g,
        (__attribute__((address_space(3))) unsigned int*)l,
        16, 0, 0);
}

#define BAR __builtin_amdgcn_s_barrier()
#define SCHEDB __builtin_amdgcn_sched_barrier(0)
#define WAITVM(N) asm volatile("s_waitcnt vmcnt(" #N ")" ::: "memory")

// stage A quadrant-half g of K-tile tt into buffer buf (2 x 64 rows)
#define STA(g, tt, buf) { \
    const _Float16* _s = Abase + (size_t)((g) * 64) * KDIM + (tt) * 64; \
    _Float16* _d = AsSt + (buf) * 16384 + (g) * 8192; \
    gload_lds16(_s, _d); \
    gload_lds16(_s + (size_t)128 * KDIM, _d + 4096); }

// stage B n-half h of K-tile tt into buffer buf
#define STB(h, tt, buf) { \
    const int _sg = (tt) >> 4; \
    const _Float16* _s = Bbase + ((size_t)(comp ^ _sg) << 20) \
                       + (size_t)((h) * 128) * 1024 + ((tt) & 15) * 64; \
    _Float16* _d = BsSt + (buf) * 16384 + (h) * 8192; \
    gload_lds16(_s, _d); \
    gload_lds16(_s + 64 * 1024, _d + 4096); }

#define RDA(AF, BASE, g, SL) { \
    const _Float16* _p = (BASE) + (g) * 8192 + arow + (SL); \
    AF[0] = *(const half8*)(_p); \
    AF[1] = *(const half8*)(_p + 1024); \
    AF[2] = *(const half8*)(_p + 2048); \
    AF[3] = *(const half8*)(_p + 3072); }

#define RDB(BQ, BASE, SL, NEG) { \
    const _Float16* _p = (BASE) + bnh * 8192 + brow + (SL); \
    BQ[0] = *(const half8*)(_p); \
    BQ[1] = *(const half8*)(_p + 1024); \
    BQ[2] = *(const half8*)(_p + 2048); \
    BQ[3] = *(const half8*)(_p + 3072); \
    if (NEG) { BQ[0] = -BQ[0]; BQ[1] = -BQ[1]; BQ[2] = -BQ[2]; BQ[3] = -BQ[3]; } }

#define MFMA16(IB, AF, BQ) \
    _Pragma("unroll") \
    for (int _i = 0; _i < 4; _i++) \
      _Pragma("unroll") \
      for (int _j = 0; _j < 4; _j++) \
        acc[(IB) + _i][_j] = __builtin_amdgcn_mfma_f32_16x16x32_f16( \
            AF[_i], BQ[_j], acc[(IB) + _i][_j], 0, 0, 0);

__global__ __launch_bounds__(512, 2) void gemm_kernel(
        const _Float16* __restrict__ A,      // [4096,4096] fp16
        const _Float16* __restrict__ Wh,     // [4][1024][1024] fp16
        const float* __restrict__ b0, const float* __restrict__ b1,
        const float* __restrict__ b2, const float* __restrict__ b3,
        float* __restrict__ C) {
    __shared__ _Float16 lds[65536];          // 128 KiB
    _Float16* As = lds;                      // [buf][g][8192]
    _Float16* Bs = lds + 32768;              // [buf][nh][8192]

    const int tid  = threadIdx.x;
    const int lane = tid & 63;
    const int wave = tid >> 6;               // 0..7
    const int wmh  = wave >> 2;              // M-half of 256-row tile (0/1)
    const int wn   = (wave & 3) * 64;        // N offset within 256-col tile
    const int bnh  = wn >> 7;                // which B n-half this wave reads
    const int broff = (wn & 64) * 64;        // row base (halves) within B region

    // bijective XCD swizzle (nwg=256 divisible by 8): each XCD gets 2 full
    // bm-rows (all 16 bn) -> A panels L2-local per XCD.
    const int wg = ((blockIdx.x & 7) << 5) | (blockIdx.x >> 3);
    const int bm = wg >> 4, bn = wg & 15;
    const int m0 = bm << 8;
    const int n0 = bn << 8;
    const int comp = bn >> 2;                // output quaternion component
    const int n0q  = n0 & 1023;

    // staging geometry: 8 threads/row, 16B chunks, slot s holds chunk s^(row&7)
    const int lrow = tid >> 3;               // 0..63
    const int gch  = (tid & 7) ^ (lrow & 7);
    const _Float16* Abase = A  + (size_t)(m0  + lrow) * KDIM + gch * 8;
    const _Float16* Bbase = Wh + (size_t)(n0q + lrow) * 1024 + gch * 8;
    _Float16* AsSt = As + tid * 8;
    _Float16* BsSt = Bs + tid * 8;

    // fragment geometry (16x16x32): m/n = fr, k = kh*32 + qf*8 + j
    const int fr  = lane & 15;
    const int qf  = lane >> 4;
    const int fsw = fr & 7;
    const int sl0 = ((0 + qf) ^ fsw) * 8;    // kh=0 slot (halves)
    const int sl1 = ((4 + qf) ^ fsw) * 8;    // kh=1 slot
    const int arow = wmh * 4096 + fr * 64;   // within A quadrant region
    const int brow = broff + fr * 64;        // within B n-half region

    // signs: one negated segment per comp + global flip (comp0 only)
    const int negseg = (comp == 0) ? 0 : (comp == 1) ? 3 : (comp == 2) ? 1 : 2;
    const float flip = (comp == 0) ? -1.f : 1.f;

    floatx4 acc[8][4];
#pragma unroll
    for (int i = 0; i < 8; i++)
#pragma unroll
        for (int j = 0; j < 4; j++)
            acc[i][j] = (floatx4){0.f, 0.f, 0.f, 0.f};

    half8 afP[4], afQ[4], bf0[4], bf1[4];

    // ---- prologue: tile0 fully + Ag0/Bn0 of tile1; 3 half-tiles stay in flight
    STA(0, 0, 0); STB(0, 0, 0); STB(1, 0, 0); STA(1, 0, 0);
    STA(0, 1, 1); STB(0, 1, 1);
    WAITVM(6);                               // lands Ag0/Bn0/Bn1 of tile 0
    BAR;
    // prefetch F1(0): consumed at ph1 of tt=0
    RDA(afP, As, 0, sl0); RDB(bf0, Bs, sl0, (0 == negseg));

    for (int tt = 0; tt < 64; ++tt) {
        const int cur = tt & 1, nxt = cur ^ 1;
        const bool bneg  = ((tt >> 4) == negseg);          // tile tt sign (bf1)
        const _Float16* Acur = As + cur * 16384;
        const _Float16* Bcur = Bs + cur * 16384;
        const _Float16* Anxt = As + nxt * 16384;
        const _Float16* Bnxt = Bs + nxt * 16384;
        const int t1 = (tt >= 63) ? 63 : tt + 1;
        const int t2 = (tt >= 62) ? 63 : tt + 2;
        const bool bneg1 = ((t1 >> 4) == negseg);          // tile tt+1 sign (bf0')

        // ---- ph1: consume (afP=g0k0, bf0); prefetch F2 (afQ=g0k1, bf1)
        RDA(afQ, Acur, 0, sl1); RDB(bf1, Bcur, sl1, bneg);
        STB(1, t1, nxt);
        SCHEDB;
        __builtin_amdgcn_s_setprio(1);
        MFMA16(0, afP, bf0);
        __builtin_amdgcn_s_setprio(0);
        WAITVM(6);                           // lands Ag1(tt) for ph2's prefetch
        BAR;

        // ---- ph2: consume (afQ, bf1); prefetch F3 (afP=g1k0)
        RDA(afP, Acur, 1, sl0);
        STA(1, t1, nxt);
        SCHEDB;
        __builtin_amdgcn_s_setprio(1);
        MFMA16(0, afQ, bf1);
        __builtin_amdgcn_s_setprio(0);
        BAR;

        // ---- ph3: consume (afP, bf0); prefetch F4 (afQ=g1k1)
        RDA(afQ, Acur, 1, sl1);
        STA(0, t2, cur);                     // region freed (reads drained ph2)
        SCHEDB;
        __builtin_amdgcn_s_setprio(1);
        MFMA16(4, afP, bf0);
        __builtin_amdgcn_s_setprio(0);
        WAITVM(4);                           // lands Ag0/Bn0/Bn1(tt+1) for ph4
        BAR;

        // ---- ph4: consume (afQ, bf1); prefetch F1(tt+1) (afP, bf0 from nxt)
        RDA(afP, Anxt, 0, sl0); RDB(bf0, Bnxt, sl0, bneg1);
        STB(0, t2, cur);
        SCHEDB;
        __builtin_amdgcn_s_setprio(1);
        MFMA16(4, afQ, bf1);
        __builtin_amdgcn_s_setprio(0);
        BAR;
    }

    WAITVM(0);   // drain tail DMAs before LDS teardown

    // Epilogue: D[row][col], col = lane&15, row = (lane>>4)*4 + r  [m89 layout]
    const int col   = lane & 15;
    const int rquad = (lane >> 4) * 4;
    const int wm    = wmh * 128;
    const float* bsp[4] = {b0, b1, b2, b3};
#pragma unroll
    for (int j = 0; j < 4; j++) {
        const int gn = n0 + wn + j * 16 + col;
        const int o  = gn & 1023;
        float bv = 0.f;
#pragma unroll
        for (int c = 0; c < 4; c++)
            bv += d_stab[comp * 4 + c] * bsp[comp ^ c][o];
#pragma unroll
        for (int i = 0; i < 8; i++) {
            const int gmb = m0 + wm + i * 16 + rquad;
#pragma unroll
            for (int r = 0; r < 4; r++)
                C[(size_t)(gmb + r) * NDIM + gn] = flip * acc[i][j][r] + bv;
        }
    }
}

// ---------------- fp32 fallback (only if ws too small) ----------------
__global__ void fallback_kernel(const float* __restrict__ x,
                                const float* __restrict__ W0, const float* __restrict__ W1,
                                const float* __restrict__ W2, const float* __restrict__ W3,
                                const float* __restrict__ b0, const float* __restrict__ b1,
                                const float* __restrict__ b2, const float* __restrict__ b3,
                                float* __restrict__ out) {
    int idx = blockIdx.x * 256 + threadIdx.x;   // 16M outputs
    int m = idx >> 12, n = idx & 4095;
    int comp = n >> 10, o = n & 1023;
    const float* Ws[4] = {W0, W1, W2, W3};
    const float* bs[4] = {b0, b1, b2, b3};
    float acc = 0.f;
    for (int c = 0; c < 4; c++) {
        int t = comp * 4 + c;
        const float* wr = Ws[d_qtab[t]] + (size_t)o * 1024;
        const float* xr = x + (size_t)m * 4096 + c * 1024;
        float s = d_stab[t];
        float dot = 0.f;
        for (int i = 0; i < 1024; i += 4) {
            float4 wv = *(const float4*)(wr + i);
            float4 xv = *(const float4*)(xr + i);
            dot += wv.x * xv.x + wv.y * xv.y + wv.z * xv.z + wv.w * xv.w;
        }
        acc += s * dot + s * bs[d_qtab[t]][o];
    }
    out[idx] = acc;
}

// ---------------- launch ----------------
extern "C" void kernel_launch(void* const* d_in, const int* in_sizes, int n_in,
                              void* d_out, int out_size, void* d_ws, size_t ws_size,
                              hipStream_t stream) {
    const float* x = (const float*)d_in[0];
    const float* W[4];
    const float* b[4];
    int wi = 0, bi = 0;
    for (int i = 1; i < n_in && i < 9; i++) {
        if (in_sizes[i] > 4096) { if (wi < 4) W[wi++] = (const float*)d_in[i]; }
        else                    { if (bi < 4) b[bi++] = (const float*)d_in[i]; }
    }
    float* out = (float*)d_out;

    const size_t xh_elems = (size_t)MDIM * KDIM;        // 16M fp16 = 32 MB
    const size_t wh_elems = (size_t)4 * 1024 * 1024;    // 4M fp16 = 8 MB
    const size_t needed = (xh_elems + wh_elems) * 2;

    if (ws_size < needed) {
        fallback_kernel<<<(MDIM * NDIM) / 256, 256, 0, stream>>>(
            x, W[0], W[1], W[2], W[3], b[0], b[1], b[2], b[3], out);
        return;
    }

    _Float16* xh = (_Float16*)d_ws;
    _Float16* Wh = xh + xh_elems;

    prepass_kernel<<<8192 + 2048, 256, 0, stream>>>(x, W[0], W[1], W[2], W[3], xh, Wh);
    gemm_kernel<<<(MDIM / 256) * (NDIM / 256), 512, 0, stream>>>(
        xh, Wh, b[0], b[1], b[2], b[3], out);
}